// Round 3
// baseline (2679.505 us; speedup 1.0000x reference)
//
#include <hip/hip_runtime.h>

// Problem constants
#define A_N   512
#define E_DIM 64
#define H_DIM 128
#define GG    64          // G*G
#define K_CAT 320         // E + H + H  (emb | soc | h)
#define T_OBS 8
#define PRED  12
#define NBLK  512
#define NTHR  256

typedef __attribute__((ext_vector_type(8))) short bf16x8;
typedef __attribute__((ext_vector_type(4))) float f32x4;
#define MFMA16(a,b,c) __builtin_amdgcn_mfma_f32_16x16x32_bf16((a),(b),(c),0,0,0)

// workspace offsets (bytes)
#define WP_OFF   0           // 128*8192*2      = 2097152
#define WZ_OFF   2097152     // 512*320*2       = 327680
#define BZ_OFF   2424832     // 512*4           = 2048
#define MASK_OFF 2426880     // 512*4           = 2048
#define H_OFF    2428928     // 512*128*4       = 262144
#define C_OFF    2691072     // 512*128*4       = 262144
#define CUR_OFF  2953216     // 512*2*4         = 4096
#define XCAT_OFF 2957312     // 512*320*2       = 327680
#define GRID_OFF 3284992     // 512*8192*2      = 8388608
#define PART_OFF 11673600    // 16*512*128*4    = 4194304
#define BAR_OFF  15867904    // 2048*4          = 8192

static __device__ __forceinline__ unsigned short f2bf(float x){
    union { float f; unsigned u; } v; v.f = x;
    unsigned r = v.u + 0x7fffu + ((v.u >> 16) & 1u);   // RNE
    return (unsigned short)(r >> 16);
}
static __device__ __forceinline__ float sigm_f(float x){
    return 1.f / (1.f + __expf(-x));
}
static __device__ __forceinline__ float tanh_f(float x){
    float e = __expf(-2.f * fabsf(x));
    float t = (1.f - e) / (1.f + e);
    return copysignf(t, x);
}

struct SmemA {
    float acc[2][GG * H_DIM];   // 65536
    float2 pos[A_N];            // 4096
    short  cell[A_N];           // 1024
    short  list[A_N];           // 1024
    int    nvalid;              // 4
};
struct SmemC {
    unsigned short soc[16][136];  // 4352 (padded rows: 272B stride, 16B-aligned)
    float z[4][4][H_DIM];         // 8192
    float hrow[4][H_DIM];         // 2048
    float raw[4][5];              // 80
};

// two-level grid barrier: bar[0]=generation, bar[16]=root cnt, bar[32+g*16]=group cnt
static __device__ __forceinline__ void gridbar(int* bar, int bid, int& gen){
    __syncthreads();
    if (threadIdx.x == 0){
        __builtin_amdgcn_fence(__ATOMIC_RELEASE, "agent");
        gen++;
        const int g = bid >> 3;                 // 64 groups of 8
        int p = __hip_atomic_fetch_add(&bar[32 + g*16], 1, __ATOMIC_RELAXED,
                                       __HIP_MEMORY_SCOPE_AGENT);
        if (p == 7){
            __hip_atomic_store(&bar[32 + g*16], 0, __ATOMIC_RELAXED,
                               __HIP_MEMORY_SCOPE_AGENT);
            int q = __hip_atomic_fetch_add(&bar[16], 1, __ATOMIC_RELEASE,
                                           __HIP_MEMORY_SCOPE_AGENT);
            if (q == 63){
                __hip_atomic_store(&bar[16], 0, __ATOMIC_RELAXED,
                                   __HIP_MEMORY_SCOPE_AGENT);
                __hip_atomic_store(&bar[0], gen, __ATOMIC_RELEASE,
                                   __HIP_MEMORY_SCOPE_AGENT);
            }
        }
        int spins = 0;
        while (__hip_atomic_load(&bar[0], __ATOMIC_RELAXED,
                                 __HIP_MEMORY_SCOPE_AGENT) < gen){
            __builtin_amdgcn_s_sleep(2);
            if (++spins > (1 << 21)) break;    // safety bail (~0.5 s), never hit normally
        }
        __builtin_amdgcn_fence(__ATOMIC_ACQUIRE, "agent");
    }
    __syncthreads();
}

__global__ void bar_init(int* bar){
    int i = blockIdx.x * 1024 + threadIdx.x;
    if (i < 2048) bar[i] = 0;
}

__global__ __launch_bounds__(NTHR, 2) void social_persist(
    const float* __restrict__ obs, const unsigned char* __restrict__ mraw,
    const float* __restrict__ W_e, const float* __restrict__ b_e,
    const float* __restrict__ Wp,  const float* __restrict__ b_p,
    const float* __restrict__ Wih, const float* __restrict__ Whh,
    const float* __restrict__ bih, const float* __restrict__ bhh,
    const float* __restrict__ W_o, const float* __restrict__ b_o,
    unsigned short* wp_bf, unsigned short* wz, float* bz, int* mski,
    float* h, float* c, float* cur, unsigned short* xcat,
    unsigned short* grid, float* part, int* bar, float* out)
{
    __shared__ __align__(16) char smem_raw[sizeof(SmemA)];
    __shared__ int mflagA, mflagB;
    const int bid = blockIdx.x, tid = threadIdx.x;
    int gen = 0;

    // ---------------- prep: weight conversion, state init, mask decode -------
    {
        const int i0 = bid * NTHR + tid, stride = NBLK * NTHR;
        for (int i = i0; i < 128*8192; i += stride) wp_bf[i] = f2bf(Wp[i]);
        for (int i = i0; i < 512*K_CAT; i += stride){
            int n = i / K_CAT, k = i - n*K_CAT;
            float w = (k < 192) ? Wih[n*192 + k] : Whh[n*128 + (k - 192)];
            wz[i] = f2bf(w);
        }
        for (int i = i0; i < 512; i += stride) bz[i] = bih[i] + bhh[i];
        for (int i = i0; i < 512*H_DIM; i += stride){ h[i] = 0.f; c[i] = 0.f; }
        for (int i = i0; i < 512*K_CAT; i += stride) xcat[i] = 0;  // bf16 zero
        if (bid == 0){
            if (tid == 0){ mflagA = 0; mflagB = 0; }
            __syncthreads();
            for (int j = tid; j < 512; j += NTHR){
                unsigned char b = mraw[j];
                if (b && (j & 3))        atomicAdd(&mflagA, 1);
                if (b && ((j & 7) == 4)) atomicAdd(&mflagB, 1);
            }
            __syncthreads();
            for (int j = tid; j < 512; j += NTHR){
                int v;
                if (mflagA)      v = mraw[j] ? 1 : 0;
                else if (mflagB) v = ((const int*)mraw)[j] ? 1 : 0;
                else             v = ((const long long*)mraw)[j] ? 1 : 0;
                mski[j] = v;
            }
        }
    }
    gridbar(bar, bid, gen);

    for (int t = 0; t < T_OBS + PRED; ++t){
        const int mode = (t < T_OBS) ? 0 : ((t == T_OBS) ? 1 : 2);

        // ---------------- phase A: positions, cells, scatter, embedding ------
        {
            SmemA& sm = *(SmemA*)smem_raw;
            for (int j = tid; j < A_N; j += NTHR){
                float px, py;
                if (mode == 2){ px = cur[j*2]; py = cur[j*2+1]; }
                else {
                    int tt = (mode == 0) ? t : (T_OBS - 1);
                    px = obs[tt*1024 + j*2]; py = obs[tt*1024 + j*2 + 1];
                    if (isnan(px)) px = 0.f;
                    if (isnan(py)) py = 0.f;
                    if (mode == 1 && !mski[j]){ px = 0.f; py = 0.f; }
                }
                sm.pos[j] = make_float2(px, py);
            }
            __syncthreads();
            if (mode == 1 && bid == 0){
                for (int j = tid; j < A_N; j += NTHR){
                    cur[j*2] = sm.pos[j].x; cur[j*2+1] = sm.pos[j].y;
                }
            }
            const float2 pi = sm.pos[bid];
            const int vi = mski[bid];
            for (int j = tid; j < A_N; j += NTHR){
                int cc = -1;
                if (vi && j != bid && mski[j]){
                    float rx = sm.pos[j].x - pi.x, ry = sm.pos[j].y - pi.y;
                    if (fabsf(rx) < 32.f && fabsf(ry) < 32.f){
                        int col = (int)floorf((rx + 32.f) * 0.125f);
                        int row = (int)floorf((ry + 32.f) * 0.125f);
                        col = min(max(col, 0), 7); row = min(max(row, 0), 7);
                        cc = row*8 + col;
                    }
                }
                sm.cell[j] = (short)cc;
            }
            for (int k2 = tid; k2 < 2*GG*H_DIM; k2 += NTHR) ((float*)sm.acc)[k2] = 0.f;
            __syncthreads();
            if (tid < 64){
                int base = 0;
                for (int b = 0; b < 8; ++b){
                    short cj = sm.cell[b*64 + tid];
                    bool val = cj >= 0;
                    unsigned long long bal = __ballot(val);
                    int pre = __popcll(bal & ((1ull << tid) - 1ull));
                    if (val) sm.list[base + pre] = (short)((b*64 + tid) | ((int)cj << 9));
                    base += __popcll(bal);
                }
                if (tid == 0) sm.nvalid = base;
            }
            __syncthreads();
            const int nv = sm.nvalid;
            const int grp = tid >> 7, ch = tid & 127;
            float* acc = sm.acc[grp];
            int cnt = (nv - grp + 1) >> 1;
            int i = 0;
            for (; i + 4 <= cnt; i += 4){
                int p0 = sm.list[grp + 2*i];
                int p1 = sm.list[grp + 2*i + 2];
                int p2 = sm.list[grp + 2*i + 4];
                int p3 = sm.list[grp + 2*i + 6];
                float h0 = h[(p0 & 511)*H_DIM + ch];
                float h1 = h[(p1 & 511)*H_DIM + ch];
                float h2 = h[(p2 & 511)*H_DIM + ch];
                float h3 = h[(p3 & 511)*H_DIM + ch];
                acc[(p0 >> 9)*H_DIM + ch] += h0;
                acc[(p1 >> 9)*H_DIM + ch] += h1;
                acc[(p2 >> 9)*H_DIM + ch] += h2;
                acc[(p3 >> 9)*H_DIM + ch] += h3;
            }
            for (; i < cnt; ++i){
                int p0 = sm.list[grp + 2*i];
                acc[(p0 >> 9)*H_DIM + ch] += h[(p0 & 511)*H_DIM + ch];
            }
            __syncthreads();
            unsigned short* go = grid + bid * (GG*H_DIM);
            for (int k2 = tid; k2 < GG*H_DIM; k2 += NTHR)
                go[k2] = f2bf(sm.acc[0][k2] + sm.acc[1][k2]);
            if (tid < E_DIM){
                float e = W_e[tid*2]*pi.x + W_e[tid*2+1]*pi.y + b_e[tid];
                xcat[bid*K_CAT + tid] = f2bf(fmaxf(e, 0.f));
            }
        }
        gridbar(bar, bid, gen);

        // ---------------- phase B: pool GEMM, split-K 16, N-half split -------
        {
            const int mt = bid >> 5, s = (bid >> 1) & 15, nh = bid & 1;
            const int wv = tid >> 6, lane = tid & 63;
            const int m0 = mt*32 + (wv >> 1)*16;
            const int n0 = nh*64 + (wv & 1)*32;
            const int lrow = lane & 15, lk = (lane >> 4) * 8;
            f32x4 acc[2] = {};
            const unsigned short* ga  = grid + (m0 + lrow)*8192 + s*512 + lk;
            const unsigned short* gb0 = wp_bf + (n0 + lrow)*8192 + s*512 + lk;
            const unsigned short* gb1 = gb0 + 16*8192;
            #pragma unroll 4
            for (int kc = 0; kc < 16; ++kc){
                bf16x8 a  = *(const bf16x8*)(ga  + kc*32);
                bf16x8 b0 = *(const bf16x8*)(gb0 + kc*32);
                bf16x8 b1 = *(const bf16x8*)(gb1 + kc*32);
                acc[0] = MFMA16(a, b0, acc[0]);
                acc[1] = MFMA16(a, b1, acc[1]);
            }
            float* po = part + s*65536;
            const int crow = (lane >> 4) * 4, ccol = lane & 15;
            #pragma unroll
            for (int ci = 0; ci < 2; ++ci)
                #pragma unroll
                for (int r = 0; r < 4; ++r)
                    po[(m0 + crow + r)*128 + n0 + ci*16 + ccol] = acc[ci][r];
        }
        gridbar(bar, bid, gen);

        // ---------------- phase C: soc reduce + LSTM + decoder head ----------
        if (bid < 128){
            SmemC& sm = *(SmemC*)smem_raw;
            const int r0 = bid * 4;
            const int dec_t = t - T_OBS;
            for (int idx = tid; idx < 512; idx += NTHR){
                int r = idx >> 7, col = idx & 127;
                float s = b_p[col];
                #pragma unroll
                for (int k = 0; k < 16; ++k)
                    s += part[k*65536 + (r0 + r)*128 + col];
                if (!mski[r0 + r]) s = 0.f;
                sm.soc[r][col] = f2bf(s);
            }
            for (int idx = tid; idx < 12*136; idx += NTHR){
                int r = 4 + idx/136, cc2 = idx - (idx/136)*136;
                sm.soc[r][cc2] = 0;
            }
            __syncthreads();
            const int wv = tid >> 6, lane = tid & 63;
            const int lrow = lane & 15, lk = (lane >> 4) * 8;
            int arow = r0 + lrow; if (arow > 511) arow = 511;
            f32x4 acc[8] = {};
            #pragma unroll
            for (int kc = 0; kc < 10; ++kc){
                const int k0 = kc * 32;
                bf16x8 a;
                if (k0 >= 64 && k0 < 192) a = *(const bf16x8*)(&sm.soc[lrow][k0 - 64 + lk]);
                else                      a = *(const bf16x8*)(xcat + arow*K_CAT + k0 + lk);
                #pragma unroll
                for (int ci = 0; ci < 8; ++ci){
                    bf16x8 b = *(const bf16x8*)(wz + (wv*128 + ci*16 + lrow)*K_CAT + k0 + lk);
                    acc[ci] = MFMA16(a, b, acc[ci]);
                }
            }
            const int crow = (lane >> 4) * 4, ccol = lane & 15;
            #pragma unroll
            for (int ci = 0; ci < 8; ++ci)
                #pragma unroll
                for (int r = 0; r < 4; ++r){
                    int row = crow + r;
                    if (row < 4) sm.z[wv][row][ci*16 + ccol] = acc[ci][r];
                }
            __syncthreads();
            for (int idx = tid; idx < 512; idx += NTHR){
                int r = idx >> 7, col = idx & 127;
                float zi = sm.z[0][r][col] + bz[      col];
                float zf = sm.z[1][r][col] + bz[128 + col];
                float zg = sm.z[2][r][col] + bz[256 + col];
                float zo = sm.z[3][r][col] + bz[384 + col];
                float ig = sigm_f(zi);
                float fg = sigm_f(zf);
                float gv = tanh_f(zg);
                float og = sigm_f(zo);
                int gi = (r0 + r)*H_DIM + col;
                float cn = fg * c[gi] + ig * gv;
                float hn = og * tanh_f(cn);
                c[gi] = cn; h[gi] = hn;
                xcat[(r0 + r)*K_CAT + 192 + col] = f2bf(hn);
                sm.hrow[r][col] = hn;
            }
            if (dec_t >= 0){
                __syncthreads();
                if (tid < 20){
                    int a2 = tid / 5, o = tid - (tid/5)*5;
                    float s = b_o[o];
                    for (int k = 0; k < 128; ++k) s += W_o[o*128 + k] * sm.hrow[a2][k];
                    sm.raw[a2][o] = s;
                }
                __syncthreads();
                if (tid < 4){
                    int i = r0 + tid;
                    float mu0 = sm.raw[tid][0], mu1 = sm.raw[tid][1];
                    float s0 = __expf(sm.raw[tid][2]) + 1e-6f;
                    float s1 = __expf(sm.raw[tid][3]) + 1e-6f;
                    float rh = tanh_f(sm.raw[tid][4]);
                    float cx = cur[i*2], cy = cur[i*2+1];
                    if (mski[i]){ cx += mu0; cy += mu1; }
                    cur[i*2] = cx; cur[i*2+1] = cy;
                    out[dec_t*1024 + i*2]             = cx;
                    out[dec_t*1024 + i*2 + 1]         = cy;
                    out[12288 + dec_t*1024 + i*2]     = s0;
                    out[12288 + dec_t*1024 + i*2 + 1] = s1;
                    out[24576 + dec_t*512 + i]        = rh;
                }
            }
        }
        gridbar(bar, bid, gen);
    }
}

extern "C" void kernel_launch(void* const* d_in, const int* in_sizes, int n_in,
                              void* d_out, int out_size, void* d_ws, size_t ws_size,
                              hipStream_t stream)
{
    const float* obs  = (const float*)d_in[0];
    const unsigned char* mraw = (const unsigned char*)d_in[1];
    const float* W_e  = (const float*)d_in[2];
    const float* b_e  = (const float*)d_in[3];
    const float* W_p  = (const float*)d_in[4];
    const float* b_p  = (const float*)d_in[5];
    const float* W_ih = (const float*)d_in[6];
    const float* W_hh = (const float*)d_in[7];
    const float* b_ih = (const float*)d_in[8];
    const float* b_hh = (const float*)d_in[9];
    const float* W_o  = (const float*)d_in[10];
    const float* b_o  = (const float*)d_in[11];
    float* out = (float*)d_out;

    char* ws = (char*)d_ws;
    unsigned short* wp_bf = (unsigned short*)(ws + WP_OFF);
    unsigned short* wz_bf = (unsigned short*)(ws + WZ_OFF);
    float* bz   = (float*)(ws + BZ_OFF);
    int*   mski = (int*)  (ws + MASK_OFF);
    float* hbuf = (float*)(ws + H_OFF);
    float* cbuf = (float*)(ws + C_OFF);
    float* cur  = (float*)(ws + CUR_OFF);
    unsigned short* xcat = (unsigned short*)(ws + XCAT_OFF);
    unsigned short* grid = (unsigned short*)(ws + GRID_OFF);
    float* part = (float*)(ws + PART_OFF);
    int*   bar  = (int*)  (ws + BAR_OFF);

    bar_init<<<2, 1024, 0, stream>>>(bar);
    social_persist<<<NBLK, NTHR, 0, stream>>>(
        obs, mraw, W_e, b_e, W_p, b_p, W_ih, W_hh, b_ih, b_hh, W_o, b_o,
        wp_bf, wz_bf, bz, mski, hbuf, cbuf, cur, xcat, grid, part, bar, out);
}

// Round 4
// 1013.140 us; speedup vs baseline: 2.6448x; 2.6448x over previous
//
#include <hip/hip_runtime.h>

// Problem constants
#define A_N   512
#define E_DIM 64
#define H_DIM 128
#define K_CAT 320         // E + soc(128) + h(128)
#define T_OBS 8
#define PRED  12
#define NBLK  512
#define NTHR  256

typedef __attribute__((ext_vector_type(8))) short bf16x8;
typedef __attribute__((ext_vector_type(4))) float f32x4;
#define MFMA16(a,b,c) __builtin_amdgcn_mfma_f32_16x16x32_bf16((a),(b),(c),0,0,0)
#define AS __ATOMIC_RELAXED, __HIP_MEMORY_SCOPE_AGENT

// workspace offsets (bytes)
#define WP_OFF   0           // 128*8192*2 = 2097152
#define WZ_OFF   2097152     // 512*320*2  = 327680
#define BZ_OFF   2424832     // 512*4
#define MASK_OFF 2426880     // 512*4
#define CUR_OFF  2428928     // 512*2*4
#define XCAT_OFF 2433024     // 512*320*2  = 327680
#define CST_OFF  2760704     // 512*128*4  = 262144
#define U_OFF    3022848     // 512*64*128*2 = 8388608
#define BAR_OFF  11411456    // 2048*4

// ---- coherent (cross-XCD) access helpers: relaxed agent atomics, NO fences ---
static __device__ __forceinline__ void st32c(void* p, unsigned v){
    __hip_atomic_store((unsigned*)p, v, AS);
}
static __device__ __forceinline__ void st64c(void* p, unsigned long long v){
    __hip_atomic_store((unsigned long long*)p, v, AS);
}
static __device__ __forceinline__ unsigned ld32c(const void* p){
    return __hip_atomic_load((const unsigned*)p, AS);
}
static __device__ __forceinline__ unsigned long long ld64c(const void* p){
    return __hip_atomic_load((const unsigned long long*)p, AS);
}
static __device__ __forceinline__ bf16x8 ldfragc(const unsigned short* p){
    union { unsigned long long q[2]; bf16x8 v; } u;
    u.q[0] = ld64c(p); u.q[1] = ld64c(p + 4);
    return u.v;
}

static __device__ __forceinline__ unsigned short f2bf(float x){
    union { float f; unsigned u; } v; v.f = x;
    unsigned r = v.u + 0x7fffu + ((v.u >> 16) & 1u);   // RNE
    return (unsigned short)(r >> 16);
}
static __device__ __forceinline__ unsigned pack2(float a, float b){
    return (unsigned)f2bf(a) | ((unsigned)f2bf(b) << 16);
}
static __device__ __forceinline__ float bf2lo(unsigned v){ return __uint_as_float(v << 16); }
static __device__ __forceinline__ float bf2hi(unsigned v){ return __uint_as_float(v & 0xffff0000u); }
static __device__ __forceinline__ float sigm_f(float x){ return 1.f / (1.f + __expf(-x)); }
static __device__ __forceinline__ float tanh_f(float x){
    float e = __expf(-2.f * fabsf(x));
    float t = (1.f - e) / (1.f + e);
    return copysignf(t, x);
}

// grid barrier: monotonic relaxed counters only — NO acquire/release fences,
// so no buffer_wbl2 / L2-invalidate is ever emitted in the loop.
static __device__ __forceinline__ void gridbar(int* bar, int bid, int& gen){
    __syncthreads();   // compiler drains each wave's vmcnt before s_barrier
    if (threadIdx.x == 0){
        asm volatile("s_waitcnt vmcnt(0) lgkmcnt(0)" ::: "memory");
        gen++;
        int p = __hip_atomic_fetch_add(&bar[32 + (bid >> 3)*16], 1, AS);
        if ((p & 7) == 7){
            int q = __hip_atomic_fetch_add(&bar[16], 1, AS);
            if ((q & 63) == 63)
                __hip_atomic_store(&bar[0], gen, AS);
        }
        int spins = 0;
        while (__hip_atomic_load(&bar[0], AS) < gen){
            __builtin_amdgcn_s_sleep(4);
            if (++spins > (1 << 22)) break;   // safety bail: no hang, fail loud
        }
        asm volatile("" ::: "memory");
    }
    __syncthreads();
}

__global__ void bar_init(int* bar){
    int i = blockIdx.x * 1024 + threadIdx.x;
    if (i < 2048) bar[i] = 0;
}

struct SP1 { float u[64][128]; };                                          // 32 KB
struct SP2 { float2 pos[A_N]; float2 accw[4][64]; short cell[A_N];
             short list[A_N]; int nvalid; };                               // ~8.2 KB
struct SP3 { unsigned long long xa[32*80]; float zbuf[4][32][33]; };       // ~37 KB
union Smem { SP1 p1; SP2 p2; SP3 p3; };

static __device__ __forceinline__ void out_head_dev(
    int a, int tid, int dec_t, const unsigned short* xcat,
    const float* __restrict__ W_o, const float* __restrict__ b_o,
    const int* mski, float* cur, float* out)
{
    if (tid >= 64) return;
    unsigned v = ld32c((const unsigned*)xcat + a*160 + 96 + tid);  // h[2t],h[2t+1]
    float h0 = bf2lo(v), h1 = bf2hi(v);
    float p[5];
    #pragma unroll
    for (int o = 0; o < 5; ++o)
        p[o] = W_o[o*128 + 2*tid]*h0 + W_o[o*128 + 2*tid + 1]*h1;
    #pragma unroll
    for (int s = 32; s; s >>= 1)
        #pragma unroll
        for (int o = 0; o < 5; ++o) p[o] += __shfl_xor(p[o], s, 64);
    if (tid == 0){
        float mu0 = p[0] + b_o[0], mu1 = p[1] + b_o[1];
        float s0 = __expf(p[2] + b_o[2]) + 1e-6f;
        float s1 = __expf(p[3] + b_o[3]) + 1e-6f;
        float rh = tanh_f(p[4] + b_o[4]);
        union { float f[2]; unsigned long long q; } cu;
        cu.q = ld64c((const unsigned long long*)cur + a);
        if (mski[a]){ cu.f[0] += mu0; cu.f[1] += mu1; }
        st64c((unsigned long long*)cur + a, cu.q);
        out[dec_t*1024 + a*2]             = cu.f[0];
        out[dec_t*1024 + a*2 + 1]         = cu.f[1];
        out[12288 + dec_t*1024 + a*2]     = s0;
        out[12288 + dec_t*1024 + a*2 + 1] = s1;
        out[24576 + dec_t*512 + a]        = rh;
    }
}

__global__ __launch_bounds__(NTHR, 2) void social_persist(
    const float* __restrict__ obs, const unsigned char* __restrict__ mraw,
    const float* __restrict__ W_e, const float* __restrict__ b_e,
    const float* __restrict__ Wp,  const float* __restrict__ b_p,
    const float* __restrict__ Wih, const float* __restrict__ Whh,
    const float* __restrict__ bih, const float* __restrict__ bhh,
    const float* __restrict__ W_o, const float* __restrict__ b_o,
    unsigned short* wp_bf, unsigned short* wz, float* bz, int* mski,
    float* cur, unsigned short* xcat, float* cst, unsigned short* U,
    int* bar, float* out)
{
    __shared__ Smem sm;
    __shared__ int mflagA, mflagB;
    const int bid = blockIdx.x, tid = threadIdx.x;
    int gen = 0;

    // ---------------- prep: weights -> bf16 (coherent stores), init state ----
    {
        const int i0 = bid * NTHR + tid, stride = NBLK * NTHR;     // 131072
        for (int i = i0; i < 524288; i += stride)                  // W_p pairs
            st32c((unsigned*)wp_bf + i, pack2(Wp[2*i], Wp[2*i + 1]));
        for (int i = i0; i < 81920; i += stride){                  // W_z pairs
            int n = (2*i) / K_CAT, k = (2*i) - n*K_CAT;
            float w0 = (k < 192)     ? Wih[n*192 + k]     : Whh[n*128 + k - 192];
            float w1 = (k + 1 < 192) ? Wih[n*192 + k + 1] : Whh[n*128 + k + 1 - 192];
            st32c((unsigned*)wz + i, pack2(w0, w1));
        }
        for (int i = i0; i < 512; i += stride)
            st32c((unsigned*)bz + i, __float_as_uint(bih[i] + bhh[i]));
        for (int i = i0; i < 32768; i += stride)                   // c = 0
            st64c((unsigned long long*)cst + i, 0ull);
        for (int i = i0; i < 40960; i += stride)                   // xcat = 0
            st64c((unsigned long long*)xcat + i, 0ull);
        if (bid == 0){
            if (tid == 0){ mflagA = 0; mflagB = 0; }
            __syncthreads();
            for (int j = tid; j < 512; j += NTHR){
                unsigned char b = mraw[j];
                if (b && (j & 3))        atomicAdd(&mflagA, 1);
                if (b && ((j & 7) == 4)) atomicAdd(&mflagB, 1);
            }
            __syncthreads();
            for (int j = tid; j < 512; j += NTHR){
                int v;
                if (mflagA)      v = mraw[j] ? 1 : 0;
                else if (mflagB) v = ((const int*)mraw)[j] ? 1 : 0;
                else             v = ((const long long*)mraw)[j] ? 1 : 0;
                st32c(mski + j, (unsigned)v);
            }
        }
    }
    gridbar(bar, bid, gen);

    for (int t = 0; t < T_OBS + PRED; ++t){
        // ============ P1: U-GEMM  U[j][c][:] = W_c · h[j]  (+ decoder head) ==
        {
            const int c = bid >> 3, m0 = (bid & 7) * 64;
            const int w = tid >> 6, lane = tid & 63;
            const int lrow = lane & 15, lk = (lane >> 4) * 8;
            // A: h(t-1) bf16 from xcat cols 192.. (coherent frag loads)
            const unsigned short* arow = xcat + (m0 + w*16 + lrow)*K_CAT + 192 + lk;
            bf16x8 a0 = ldfragc(arow);
            bf16x8 a1 = ldfragc(arow + 32);
            bf16x8 a2 = ldfragc(arow + 64);
            bf16x8 a3 = ldfragc(arow + 96);
            f32x4 acc[8] = {};
            const unsigned short* bbase = wp_bf + lrow*8192 + c*128 + lk;
            #pragma unroll
            for (int nt = 0; nt < 8; ++nt){
                const unsigned short* bp = bbase + nt*16*8192;
                acc[nt] = MFMA16(a0, *(const bf16x8*)(bp      ), acc[nt]);
                acc[nt] = MFMA16(a1, *(const bf16x8*)(bp + 32 ), acc[nt]);
                acc[nt] = MFMA16(a2, *(const bf16x8*)(bp + 64 ), acc[nt]);
                acc[nt] = MFMA16(a3, *(const bf16x8*)(bp + 96 ), acc[nt]);
            }
            const int crow = (lane >> 4) * 4, ccol = lane & 15;
            #pragma unroll
            for (int nt = 0; nt < 8; ++nt)
                #pragma unroll
                for (int r = 0; r < 4; ++r)
                    sm.p1.u[w*16 + crow + r][nt*16 + ccol] = acc[nt][r];
            __syncthreads();
            for (int e = tid; e < 4096; e += NTHR){
                int r = e >> 6, s = e & 63;
                unsigned v = pack2(sm.p1.u[r][2*s], sm.p1.u[r][2*s + 1]);
                st32c((unsigned*)U + ((m0 + r)*64 + c)*64 + s, v);
            }
            if (t >= T_OBS + 1){
                out_head_dev(bid, tid, t - T_OBS - 1, xcat, W_o, b_o, mski, cur, out);
            } else if (t == T_OBS && tid == 0){
                // cur0 = mask ? obs_clean[T-1] : 0
                float px = obs[7*1024 + bid*2], py = obs[7*1024 + bid*2 + 1];
                if (isnan(px)) px = 0.f;
                if (isnan(py)) py = 0.f;
                if (!mski[bid]){ px = 0.f; py = 0.f; }
                union { float f[2]; unsigned long long q; } cu;
                cu.f[0] = px; cu.f[1] = py;
                st64c((unsigned long long*)cur + bid, cu.q);
            }
        }
        gridbar(bar, bid, gen);

        // ============ P2: positions, cells, gather pooled, embed =============
        {
            const int mode = (t < T_OBS) ? 0 : ((t == T_OBS) ? 1 : 2);
            if (mode == 2){
                for (int j = tid; j < A_N; j += NTHR){
                    union { float f[2]; unsigned long long q; } cu;
                    cu.q = ld64c((const unsigned long long*)cur + j);
                    sm.p2.pos[j] = make_float2(cu.f[0], cu.f[1]);
                }
            } else {
                int tt = (mode == 0) ? t : (T_OBS - 1);
                for (int j = tid; j < A_N; j += NTHR){
                    float px = obs[tt*1024 + j*2], py = obs[tt*1024 + j*2 + 1];
                    if (isnan(px)) px = 0.f;
                    if (isnan(py)) py = 0.f;
                    if (mode == 1 && !mski[j]){ px = 0.f; py = 0.f; }
                    sm.p2.pos[j] = make_float2(px, py);
                }
            }
            __syncthreads();
            const float2 pi = sm.p2.pos[bid];
            const int vi = mski[bid];
            for (int j = tid; j < A_N; j += NTHR){
                int cc = -1;
                if (vi && j != bid && mski[j]){
                    float rx = sm.p2.pos[j].x - pi.x, ry = sm.p2.pos[j].y - pi.y;
                    if (fabsf(rx) < 32.f && fabsf(ry) < 32.f){
                        int col = (int)floorf((rx + 32.f) * 0.125f);
                        int row = (int)floorf((ry + 32.f) * 0.125f);
                        col = min(max(col, 0), 7); row = min(max(row, 0), 7);
                        cc = row*8 + col;
                    }
                }
                sm.p2.cell[j] = (short)cc;
            }
            __syncthreads();
            if (tid < 64){
                int base = 0;
                for (int b = 0; b < 8; ++b){
                    short cj = sm.p2.cell[b*64 + tid];
                    bool val = cj >= 0;
                    unsigned long long bal = __ballot(val);
                    int pre = __popcll(bal & ((1ull << tid) - 1ull));
                    if (val) sm.p2.list[base + pre] = (short)((b*64 + tid) | ((int)cj << 9));
                    base += __popcll(bal);
                }
                if (tid == 0) sm.p2.nvalid = base;
            }
            __syncthreads();
            const int nv = sm.p2.nvalid;
            const int w = tid >> 6, l = tid & 63;
            const unsigned* ub = (const unsigned*)U;
            float a0 = 0.f, a1 = 0.f;
            int n = w;
            for (; n + 12 < nv; n += 16){
                int p0 = sm.p2.list[n], p1 = sm.p2.list[n+4];
                int p2 = sm.p2.list[n+8], p3 = sm.p2.list[n+12];
                unsigned v0 = ld32c(ub + ((p0 & 511) << 12) + ((p0 >> 9) << 6) + l);
                unsigned v1 = ld32c(ub + ((p1 & 511) << 12) + ((p1 >> 9) << 6) + l);
                unsigned v2 = ld32c(ub + ((p2 & 511) << 12) + ((p2 >> 9) << 6) + l);
                unsigned v3 = ld32c(ub + ((p3 & 511) << 12) + ((p3 >> 9) << 6) + l);
                a0 += bf2lo(v0); a1 += bf2hi(v0);
                a0 += bf2lo(v1); a1 += bf2hi(v1);
                a0 += bf2lo(v2); a1 += bf2hi(v2);
                a0 += bf2lo(v3); a1 += bf2hi(v3);
            }
            for (; n < nv; n += 4){
                int p0 = sm.p2.list[n];
                unsigned v0 = ld32c(ub + ((p0 & 511) << 12) + ((p0 >> 9) << 6) + l);
                a0 += bf2lo(v0); a1 += bf2hi(v0);
            }
            sm.p2.accw[w][l] = make_float2(a0, a1);
            __syncthreads();
            if (tid < 64){
                float s0 = sm.p2.accw[0][tid].x + sm.p2.accw[1][tid].x
                         + sm.p2.accw[2][tid].x + sm.p2.accw[3][tid].x + b_p[2*tid];
                float s1 = sm.p2.accw[0][tid].y + sm.p2.accw[1][tid].y
                         + sm.p2.accw[2][tid].y + sm.p2.accw[3][tid].y + b_p[2*tid + 1];
                if (!vi){ s0 = 0.f; s1 = 0.f; }
                st32c((unsigned*)xcat + bid*160 + 32 + tid, pack2(s0, s1));
            } else if (tid < 96){
                int p2_ = tid - 64;      // emb col pair
                float e0 = fmaxf(W_e[(2*p2_    )*2]*pi.x + W_e[(2*p2_    )*2 + 1]*pi.y + b_e[2*p2_    ], 0.f);
                float e1 = fmaxf(W_e[(2*p2_ + 1)*2]*pi.x + W_e[(2*p2_ + 1)*2 + 1]*pi.y + b_e[2*p2_ + 1], 0.f);
                st32c((unsigned*)xcat + bid*160 + p2_, pack2(e0, e1));
            }
        }
        gridbar(bar, bid, gen);

        // ============ P3: LSTM (64 blocks) ===================================
        if (bid < 64){
            const int rt = bid >> 2, ct = bid & 3, m0 = rt * 32;
            // stage A-tile (32 rows x 320) into LDS via coherent u64 loads
            for (int e = tid; e < 2560; e += NTHR){
                int r = e / 80, o = e - (e / 80) * 80;
                sm.p3.xa[r*80 + o] = ld64c((const unsigned long long*)xcat + (m0 + r)*80 + o);
            }
            __syncthreads();
            const int g = tid >> 6, lane = tid & 63;
            const int lrow = lane & 15, lk = (lane >> 4) * 8;
            const unsigned short* xa16 = (const unsigned short*)sm.p3.xa;
            f32x4 acc[2][2] = {};
            #pragma unroll
            for (int kc = 0; kc < 10; ++kc){
                bf16x8 a0 = *(const bf16x8*)(xa16 + lrow*K_CAT + kc*32 + lk);
                bf16x8 a1 = *(const bf16x8*)(xa16 + (16 + lrow)*K_CAT + kc*32 + lk);
                #pragma unroll
                for (int ci = 0; ci < 2; ++ci){
                    const unsigned short* bp = wz + (g*128 + ct*32 + ci*16 + lrow)*K_CAT + kc*32 + lk;
                    bf16x8 b = *(const bf16x8*)bp;
                    acc[0][ci] = MFMA16(a0, b, acc[0][ci]);
                    acc[1][ci] = MFMA16(a1, b, acc[1][ci]);
                }
            }
            const int crow = (lane >> 4) * 4, ccol = lane & 15;
            #pragma unroll
            for (int mi = 0; mi < 2; ++mi)
                #pragma unroll
                for (int ci = 0; ci < 2; ++ci)
                    #pragma unroll
                    for (int r = 0; r < 4; ++r)
                        sm.p3.zbuf[g][mi*16 + crow + r][ci*16 + ccol] = acc[mi][ci][r];
            __syncthreads();
            float* hp = (float*)sm.p3.xa;   // alias: xa no longer needed
            for (int idx = tid; idx < 1024; idx += NTHR){
                int r = idx >> 5, lc = idx & 31;
                int col = ct*32 + lc;
                float zi = sm.p3.zbuf[0][r][lc] + bz[      col];
                float zf = sm.p3.zbuf[1][r][lc] + bz[128 + col];
                float zg = sm.p3.zbuf[2][r][lc] + bz[256 + col];
                float zo = sm.p3.zbuf[3][r][lc] + bz[384 + col];
                float ig = sigm_f(zi), fg = sigm_f(zf);
                float gv = tanh_f(zg), og = sigm_f(zo);
                int gi = (m0 + r)*H_DIM + col;           // block-private: normal access
                float cn = fg * cst[gi] + ig * gv;
                float hn = og * tanh_f(cn);
                cst[gi] = cn;
                hp[r*33 + lc] = hn;
            }
            __syncthreads();
            for (int idx = tid; idx < 512; idx += NTHR){
                int r = idx >> 4, pp = idx & 15;
                unsigned v = pack2(hp[r*33 + 2*pp], hp[r*33 + 2*pp + 1]);
                st32c((unsigned*)xcat + (m0 + r)*160 + 96 + ct*16 + pp, v);
            }
        }
        gridbar(bar, bid, gen);
    }

    // tail: final decoder head (d = 11) from h(19)
    out_head_dev(bid, tid, PRED - 1, xcat, W_o, b_o, mski, cur, out);
}

extern "C" void kernel_launch(void* const* d_in, const int* in_sizes, int n_in,
                              void* d_out, int out_size, void* d_ws, size_t ws_size,
                              hipStream_t stream)
{
    const float* obs  = (const float*)d_in[0];
    const unsigned char* mraw = (const unsigned char*)d_in[1];
    const float* W_e  = (const float*)d_in[2];
    const float* b_e  = (const float*)d_in[3];
    const float* W_p  = (const float*)d_in[4];
    const float* b_p  = (const float*)d_in[5];
    const float* W_ih = (const float*)d_in[6];
    const float* W_hh = (const float*)d_in[7];
    const float* b_ih = (const float*)d_in[8];
    const float* b_hh = (const float*)d_in[9];
    const float* W_o  = (const float*)d_in[10];
    const float* b_o  = (const float*)d_in[11];
    float* out = (float*)d_out;

    char* ws = (char*)d_ws;
    unsigned short* wp_bf = (unsigned short*)(ws + WP_OFF);
    unsigned short* wz_bf = (unsigned short*)(ws + WZ_OFF);
    float* bz   = (float*)(ws + BZ_OFF);
    int*   mski = (int*)  (ws + MASK_OFF);
    float* cur  = (float*)(ws + CUR_OFF);
    unsigned short* xcat = (unsigned short*)(ws + XCAT_OFF);
    float* cst  = (float*)(ws + CST_OFF);
    unsigned short* U = (unsigned short*)(ws + U_OFF);
    int*   bar  = (int*)  (ws + BAR_OFF);

    bar_init<<<2, 1024, 0, stream>>>(bar);
    social_persist<<<NBLK, NTHR, 0, stream>>>(
        obs, mraw, W_e, b_e, W_p, b_p, W_ih, W_hh, b_ih, b_hh, W_o, b_o,
        wp_bf, wz_bf, bz, mski, cur, xcat, cst, U, bar, out);
}